// Round 12
// baseline (254.040 us; speedup 1.0000x reference)
//
#include <hip/hip_runtime.h>
#include <cstdint>

#define D_MODEL 1024
#define SEQ 2048
#define BATCH 8
#define M_TOTAL (BATCH*SEQ)   // 16384
#define NC 64                 // scan chunks per sequence
#define CL (SEQ/NC)           // 32 steps per chunk

typedef float f32x4 __attribute__((ext_vector_type(4)));
typedef short bf16x8 __attribute__((ext_vector_type(8)));
typedef unsigned short u16x4 __attribute__((ext_vector_type(4)));

__device__ __forceinline__ float b2f(unsigned short s){
  union { float f; unsigned u; } z; z.u = ((unsigned)s) << 16; return z.f;
}
__device__ __forceinline__ unsigned short f2b(float f){
  union { float f; unsigned u; } z; z.f = f;
  unsigned u = z.u;
  u += 0x7fffu + ((u >> 16) & 1u);   // round-to-nearest-even
  return (unsigned short)(u >> 16);
}
__device__ __forceinline__ float sigmoidf_(float v){
  return 1.0f / (1.0f + __expf(-v));
}
__device__ __forceinline__ void gld_lds16(const void* g, void* l){
  __builtin_amdgcn_global_load_lds((const __attribute__((address_space(1))) unsigned int*)g,
                                   (__attribute__((address_space(3))) unsigned int*)l,
                                   16, 0, 0);
}

// XCD-chunked swizzle for 512-block GEMM grid (64 m-panels x 8 n-panels). [T1]
__device__ __forceinline__ void swz_mn(int bid, int& m0, int& n0){
  int xcd = bid & 7;
  int loc = bid >> 3;              // 0..63
  int wg  = xcd*64 + loc;
  m0 = (wg >> 3) * 256;
  n0 = (wg & 7) * 128;
}

// ---------------- fused prep: lnmix (blocks 0..2047) + weight convert (2048..6143) ----------------
__global__ __launch_bounds__(256) void prep_kernel(const float* __restrict__ x,
                                                   const float* __restrict__ lnw, const float* __restrict__ lnb,
                                                   const float* __restrict__ tmk, const float* __restrict__ tmv,
                                                   const float* __restrict__ tmr,
                                                   unsigned short* __restrict__ XK, unsigned short* __restrict__ XV,
                                                   unsigned short* __restrict__ XR,
                                                   const float* __restrict__ W0, const float* __restrict__ W1,
                                                   const float* __restrict__ W2, const float* __restrict__ W3,
                                                   unsigned short* __restrict__ WC){
  int tid = threadIdx.x;
  if (blockIdx.x >= M_TOTAL/8){
    // ---- weight convert fp32 -> bf16 ----
    int t = blockIdx.x - M_TOTAL/8;      // 0..4095
    int mat = t >> 10;
    const float* src = (mat==0) ? W0 : (mat==1) ? W1 : (mat==2) ? W2 : W3;
    size_t i = ((size_t)(t & 1023)*256 + tid)*4;
    f32x4 v = *(const f32x4*)(src + i);
    u16x4 o; o[0]=f2b(v[0]); o[1]=f2b(v[1]); o[2]=f2b(v[2]); o[3]=f2b(v[3]);
    *(u16x4*)(WC + (size_t)mat*1048576 + i) = o;
    return;
  }
  // ---- LayerNorm + time-mix, row-blocked (8 rows + halo) ----
  int r0 = blockIdx.x * 8;
  bool seqfirst = (r0 & (SEQ-1)) == 0;
  size_t col = (size_t)tid*4;

  f32x4 xr[9];
  float s1[9], s2[9];
  #pragma unroll
  for (int i=0;i<9;i++){
    if (i==0 && seqfirst){
      xr[0][0]=0.f; xr[0][1]=0.f; xr[0][2]=0.f; xr[0][3]=0.f;
    } else {
      xr[i] = *(const f32x4*)(x + (size_t)(r0-1+i)*D_MODEL + col);
    }
    s1[i] = xr[i][0]+xr[i][1]+xr[i][2]+xr[i][3];
    s2[i] = xr[i][0]*xr[i][0]+xr[i][1]*xr[i][1]+xr[i][2]*xr[i][2]+xr[i][3]*xr[i][3];
  }
  #pragma unroll
  for (int off = 32; off > 0; off >>= 1){
    #pragma unroll
    for (int i=0;i<9;i++){
      s1[i] += __shfl_xor(s1[i], off);
      s2[i] += __shfl_xor(s2[i], off);
    }
  }
  __shared__ float red[4][18];
  int w = tid >> 6, lane = tid & 63;
  if (lane == 0){
    #pragma unroll
    for (int i=0;i<9;i++){ red[w][i]=s1[i]; red[w][9+i]=s2[i]; }
  }
  __syncthreads();
  float mean[9], rstd[9];
  #pragma unroll
  for (int i=0;i<9;i++){
    float a = red[0][i]+red[1][i]+red[2][i]+red[3][i];
    float b = red[0][9+i]+red[1][9+i]+red[2][9+i]+red[3][9+i];
    mean[i] = a*(1.0f/1024.0f);
    float var = b*(1.0f/1024.0f) - mean[i]*mean[i];
    rstd[i] = rsqrtf(var + 1e-5f);
  }

  f32x4 wv = *(const f32x4*)(lnw + col);
  f32x4 bv = *(const f32x4*)(lnb + col);
  f32x4 k4 = *(const f32x4*)(tmk + col);
  f32x4 v4 = *(const f32x4*)(tmv + col);
  f32x4 r4 = *(const f32x4*)(tmr + col);

  f32x4 np;
  if (seqfirst){ np[0]=0.f; np[1]=0.f; np[2]=0.f; np[3]=0.f; }
  else {
    #pragma unroll
    for (int j=0;j<4;j++) np[j] = (xr[0][j]-mean[0])*rstd[0]*wv[j] + bv[j];
  }
  #pragma unroll
  for (int i=0;i<8;i++){
    f32x4 nc;
    #pragma unroll
    for (int j=0;j<4;j++) nc[j] = (xr[i+1][j]-mean[i+1])*rstd[i+1]*wv[j] + bv[j];
    u16x4 ok, ov, orr;
    #pragma unroll
    for (int j=0;j<4;j++){
      ok[j]  = f2b(np[j] + k4[j]*(nc[j]-np[j]));
      ov[j]  = f2b(np[j] + v4[j]*(nc[j]-np[j]));
      orr[j] = f2b(np[j] + r4[j]*(nc[j]-np[j]));
    }
    size_t base = (size_t)(r0+i)*D_MODEL + col;
    *(u16x4*)(XK + base) = ok;
    *(u16x4*)(XV + base) = ov;
    *(u16x4*)(XR + base) = orr;
    np = nc;
  }
}

// ---------------- 256x128 GEMM core, minimal-barrier variant ----------------
// BK=64, 4 waves (2m x 2n, wave tile 128x64), SINGLE 48KB LDS buffer ->
// 2 blocks/CU (m114 inter-block overlap). Per K-tile only TWO barriers
// (the hazard-carrying ones): (1) top: vmcnt(0)+bar = staging visible;
// (2) after batched ds_reads: lgkm(0)+sched_barrier+bar = all waves'
// reads done -> STAGE(kt+1) overwrite race-free. All 64 MFMAs run as one
// register-only cluster under setprio, covering the 12 in-flight staging
// loads. Compiler schedules the 24 ds_reads with fine-grained lgkmcnt.
// 2-way-free XOR swizzle unchanged. [r8 geometry, pacing barriers removed]
__device__ __forceinline__ void gemm256_core(const unsigned short* __restrict__ A,
                                             const unsigned short* __restrict__ W,
                                             int m0, int n0, int tid,
                                             unsigned short* As, unsigned short* Bs,
                                             f32x4 (&acc)[8][4]){
  int wid = tid >> 6, lane = tid & 63;
  int wm = wid >> 1, wn = wid & 1;        // 2 x 2 waves
  int fr = lane & 15, fg = lane >> 4;

  // staging offsets: A 8 chunks/thread, B 4 chunks/thread per K-tile.
  // source pre-swizzled; LDS linear (gld_lds constraint, both-sides rule).
  int offAg[8], offBg[4];
  #pragma unroll
  for (int it = 0; it < 8; ++it){
    int chunk = it*256 + tid;          // 0..2047
    int row = chunk >> 3;              // 0..255
    int cg = (chunk & 7) ^ (row & 7);
    offAg[it] = (m0+row)*D_MODEL + cg*8;
  }
  #pragma unroll
  for (int it = 0; it < 4; ++it){
    int chunk = it*256 + tid;          // 0..1023
    int row = chunk >> 3;              // 0..127
    int cg = (chunk & 7) ^ (row & 7);
    offBg[it] = (n0+row)*D_MODEL + cg*8;
  }

  #define STAGE(kt_) { \
    _Pragma("unroll") \
    for (int it = 0; it < 8; ++it) \
      gld_lds16(A + offAg[it] + (kt_)*64, &As[(it*256+tid)*8]); \
    _Pragma("unroll") \
    for (int it = 0; it < 4; ++it) \
      gld_lds16(W + offBg[it] + (kt_)*64, &Bs[(it*256+tid)*8]); \
  }

  STAGE(0);

  bf16x8 a[8][2], b[4][2];

  #pragma unroll 1
  for (int kt = 0; kt < 16; ++kt){
    // (1) staging for tile kt visible to all waves
    asm volatile("s_waitcnt vmcnt(0)" ::: "memory");
    __builtin_amdgcn_s_barrier();
    asm volatile("" ::: "memory");

    // batched fragment reads (compiler interleaves with fine lgkmcnt)
    #pragma unroll
    for (int mi=0; mi<8; ++mi)
      #pragma unroll
      for (int ks=0; ks<2; ++ks){
        int r = wm*128 + mi*16 + fr;
        a[mi][ks] = *(const bf16x8*)(&As[r*64 + (((ks*4+fg)^(r&7))<<3)]);
      }
    #pragma unroll
    for (int ni=0; ni<4; ++ni)
      #pragma unroll
      for (int ks=0; ks<2; ++ks){
        int r = wn*64 + ni*16 + fr;
        b[ni][ks] = *(const bf16x8*)(&Bs[r*64 + (((ks*4+fg)^(r&7))<<3)]);
      }

    // (2) all waves' reads complete -> single-buffer overwrite is safe
    asm volatile("s_waitcnt lgkmcnt(0)" ::: "memory");
    __builtin_amdgcn_sched_barrier(0);     // rule #18: no MFMA hoisting past lgkm
    __builtin_amdgcn_s_barrier();
    asm volatile("" ::: "memory");

    if (kt < 15) STAGE(kt+1);   // 12 loads in flight under 64 reg-only MFMAs + other block

    __builtin_amdgcn_s_setprio(1);
    #pragma unroll
    for (int mi=0; mi<8; ++mi)
      #pragma unroll
      for (int ni=0; ni<4; ++ni)
        #pragma unroll
        for (int ks=0; ks<2; ++ks)
          acc[mi][ni] = __builtin_amdgcn_mfma_f32_16x16x32_bf16(a[mi][ks], b[ni][ks], acc[mi][ni], 0, 0, 0);
    __builtin_amdgcn_s_setprio(0);
  }
  #undef STAGE
}

// ---------------- k and r GEMMs: z=0 k->KB, z=1 sigmoid r->RB ----------------
__global__ __launch_bounds__(256, 2) void gemm_kr_kernel(const unsigned short* __restrict__ XK,
                                                         const unsigned short* __restrict__ XR,
                                                         const unsigned short* __restrict__ Wk,
                                                         const unsigned short* __restrict__ Wr,
                                                         unsigned short* __restrict__ KB,
                                                         unsigned short* __restrict__ RB){
  __shared__ alignas(16) unsigned short As[16384];  // 32 KiB
  __shared__ alignas(16) unsigned short Bs[8192];   // 16 KiB
  int m0, n0; swz_mn(blockIdx.x, m0, n0);
  int z = blockIdx.z;
  int tid = threadIdx.x;
  const unsigned short* A = z ? XR : XK;
  const unsigned short* W = z ? Wr : Wk;
  unsigned short* O       = z ? RB : KB;

  f32x4 acc[8][4];
  #pragma unroll
  for (int i=0;i<8;i++)
    #pragma unroll
    for (int j=0;j<4;j++){ acc[i][j][0]=0.f; acc[i][j][1]=0.f; acc[i][j][2]=0.f; acc[i][j][3]=0.f; }

  gemm256_core(A, W, m0, n0, tid, As, Bs, acc);

  int wid = tid >> 6, lane = tid & 63;
  int wm = wid >> 1, wn = wid & 1;
  int fr = lane & 15, fg = lane >> 4;
  #pragma unroll
  for (int mi=0; mi<8; ++mi){
    #pragma unroll
    for (int ni=0; ni<4; ++ni){
      int c = n0 + wn*64 + ni*16 + fr;
      #pragma unroll
      for (int j=0; j<4; ++j){
        int r = m0 + wm*128 + mi*16 + fg*4 + j;
        size_t idx = (size_t)r*D_MODEL + c;
        float val = acc[mi][ni][j];
        if (z) val = sigmoidf_(val);
        O[idx] = f2b(val);
      }
    }
  }
}

// ---------------- v GEMM: kv = v*k RMW into KB (k from prior dispatch) ----------------
__global__ __launch_bounds__(256, 2) void gemm_v_kernel(const unsigned short* __restrict__ XV,
                                                        const unsigned short* __restrict__ Wv,
                                                        unsigned short* __restrict__ KB){
  __shared__ alignas(16) unsigned short As[16384];
  __shared__ alignas(16) unsigned short Bs[8192];
  int m0, n0; swz_mn(blockIdx.x, m0, n0);
  int tid = threadIdx.x;

  f32x4 acc[8][4];
  #pragma unroll
  for (int i=0;i<8;i++)
    #pragma unroll
    for (int j=0;j<4;j++){ acc[i][j][0]=0.f; acc[i][j][1]=0.f; acc[i][j][2]=0.f; acc[i][j][3]=0.f; }

  gemm256_core(XV, Wv, m0, n0, tid, As, Bs, acc);

  int wid = tid >> 6, lane = tid & 63;
  int wm = wid >> 1, wn = wid & 1;
  int fr = lane & 15, fg = lane >> 4;
  #pragma unroll
  for (int mi=0; mi<8; ++mi){
    #pragma unroll
    for (int ni=0; ni<4; ++ni){
      int c = n0 + wn*64 + ni*16 + fr;
      #pragma unroll
      for (int j=0; j<4; ++j){
        int r = m0 + wm*128 + mi*16 + fg*4 + j;
        size_t idx = (size_t)r*D_MODEL + c;
        KB[idx] = f2b(acc[mi][ni][j] * b2f(KB[idx]));   // kv = v*k
      }
    }
  }
}

// ---------------- out GEMM: o = S_seq @ Wo^T ; out = x + r*o ----------------
__global__ __launch_bounds__(256, 2) void gemm_out_kernel(const unsigned short* __restrict__ Sb,
                                                          const unsigned short* __restrict__ Wo,
                                                          const float* __restrict__ x,
                                                          const unsigned short* __restrict__ RB,
                                                          float* __restrict__ out){
  __shared__ alignas(16) unsigned short As[16384];
  __shared__ alignas(16) unsigned short Bs[8192];
  int m0, n0; swz_mn(blockIdx.x, m0, n0);
  int tid = threadIdx.x;

  f32x4 acc[8][4];
  #pragma unroll
  for (int i=0;i<8;i++)
    #pragma unroll
    for (int j=0;j<4;j++){ acc[i][j][0]=0.f; acc[i][j][1]=0.f; acc[i][j][2]=0.f; acc[i][j][3]=0.f; }

  gemm256_core(Sb, Wo, m0, n0, tid, As, Bs, acc);

  int wid = tid >> 6, lane = tid & 63;
  int wm = wid >> 1, wn = wid & 1;
  int fr = lane & 15, fg = lane >> 4;
  #pragma unroll
  for (int mi=0; mi<8; ++mi){
    #pragma unroll
    for (int ni=0; ni<4; ++ni){
      int c = n0 + wn*64 + ni*16 + fr;
      #pragma unroll
      for (int j=0; j<4; ++j){
        int r = m0 + wm*128 + mi*16 + fg*4 + j;
        size_t idx = (size_t)r*D_MODEL + c;
        float rr = b2f(RB[idx]);
        out[idx] = x[idx] + rr * acc[mi][ni][j];
      }
    }
  }
}

// ---------------- scan phase 1: per-chunk carries (reads kv) ----------------
__global__ __launch_bounds__(256) void scan_p1_kernel(const unsigned short* __restrict__ kv,
                                                      const float* __restrict__ dw,
                                                      float* __restrict__ carr){
  int bc = blockIdx.x;            // b*NC + c
  int b = bc >> 6, c = bc & (NC-1);
  int d0 = threadIdx.x * 4;
  float dx = sigmoidf_(dw[d0+0]);
  float dy = sigmoidf_(dw[d0+1]);
  float dz = sigmoidf_(dw[d0+2]);
  float dwv = sigmoidf_(dw[d0+3]);
  float Sx=0.f, Sy=0.f, Sz=0.f, Sw=0.f;
  size_t base = ((size_t)(b*SEQ + c*CL))*D_MODEL + d0;
  for (int i=0;i<CL;i++){
    u16x4 k4 = *(const u16x4*)(kv + base);
    Sx = dx*Sx + b2f(k4[0]);
    Sy = dy*Sy + b2f(k4[1]);
    Sz = dz*Sz + b2f(k4[2]);
    Sw = dwv*Sw + b2f(k4[3]);
    base += D_MODEL;
  }
  f32x4 o; o[0]=Sx; o[1]=Sy; o[2]=Sz; o[3]=Sw;
  *(f32x4*)(carr + (size_t)bc*D_MODEL + d0) = o;
}

// ---------------- scan phase 2: cross-chunk exclusive scan (in-place) ----------------
__global__ __launch_bounds__(256) void scan_p2_kernel(const float* __restrict__ dw, float* __restrict__ carr){
  int gid = blockIdx.x*256 + threadIdx.x;   // 0..8191
  int b = gid >> 10, d = gid & (D_MODEL-1);
  float dec = sigmoidf_(dw[d]);
  float dL = dec;
  #pragma unroll
  for (int i=0;i<5;i++) dL *= dL;           // dec^32
  float S = 0.f;
  for (int c=0;c<NC;c++){
    size_t idx = ((size_t)(b*NC + c))*D_MODEL + d;
    float cr = carr[idx];
    carr[idx] = S;                          // becomes carry-in
    S = dL*S + cr;
  }
}

// ---------------- scan phase 3: prefix with carry-in; write S_seq fp32 + bf16 ----------------
__global__ __launch_bounds__(256) void scan_p3_kernel(const unsigned short* __restrict__ kv,
                                                      const float* __restrict__ dw,
                                                      const float* __restrict__ cin,
                                                      float* __restrict__ sseq,
                                                      float* __restrict__ finalS,
                                                      unsigned short* __restrict__ sb16){
  int bc = blockIdx.x;
  int b = bc >> 6, c = bc & (NC-1);
  int d0 = threadIdx.x * 4;
  float dx = sigmoidf_(dw[d0+0]);
  float dy = sigmoidf_(dw[d0+1]);
  float dz = sigmoidf_(dw[d0+2]);
  float dwv = sigmoidf_(dw[d0+3]);
  f32x4 S = *(const f32x4*)(cin + (size_t)bc*D_MODEL + d0);
  size_t base = ((size_t)(b*SEQ + c*CL))*D_MODEL + d0;
  for (int i=0;i<CL;i++){
    u16x4 k4 = *(const u16x4*)(kv + base);
    S[0] = dx*S[0] + b2f(k4[0]);
    S[1] = dy*S[1] + b2f(k4[1]);
    S[2] = dz*S[2] + b2f(k4[2]);
    S[3] = dwv*S[3] + b2f(k4[3]);
    *(f32x4*)(sseq + base) = S;
    u16x4 s4; s4[0]=f2b(S[0]); s4[1]=f2b(S[1]); s4[2]=f2b(S[2]); s4[3]=f2b(S[3]);
    *(u16x4*)(sb16 + base) = s4;
    base += D_MODEL;
  }
  if (c == NC-1)
    *(f32x4*)(finalS + (size_t)b*D_MODEL + d0) = S;
}

extern "C" void kernel_launch(void* const* d_in, const int* in_sizes, int n_in,
                              void* d_out, int out_size, void* d_ws, size_t ws_size,
                              hipStream_t stream){
  const float* x   = (const float*)d_in[0];
  const float* lnw = (const float*)d_in[1];
  const float* lnb = (const float*)d_in[2];
  const float* tmk = (const float*)d_in[3];
  const float* tmv = (const float*)d_in[4];
  const float* tmr = (const float*)d_in[5];
  const float* dw  = (const float*)d_in[6];
  const float* Wk  = (const float*)d_in[7];
  const float* Wv  = (const float*)d_in[8];
  const float* Wr  = (const float*)d_in[9];
  const float* Wo  = (const float*)d_in[10];

  float* out    = (float*)d_out;
  float* finalS = out + (size_t)M_TOTAL*D_MODEL;
  float* sseq   = finalS + (size_t)BATCH*D_MODEL;

  // d_out doubles as GEMM-phase scratch:
  //   XK = out[0 .. 33.5MB)           dead before gemm_out writes out
  //   XV = out[33.5MB .. 67.1MB)      dead before gemm_out writes out
  //   XR = sseq region (first 33.5MB) dead before scan_p3 writes sseq
  unsigned short* XK = (unsigned short*)d_out;
  unsigned short* XV = (unsigned short*)((char*)d_out + 33554432);
  unsigned short* XR = (unsigned short*)sseq;

  char* w = (char*)d_ws;
  unsigned short* WC   = (unsigned short*)(w + 0);           // 8.4 MB (Wk,Wv,Wr,Wo bf16)
  unsigned short* SB16 = (unsigned short*)(w + 8388608);     // 33.5 MB: S bf16 for out-GEMM
  unsigned short* KB   = (unsigned short*)(w + 41943040);    // 33.5 MB: k, then kv (RMW)
  unsigned short* RB   = (unsigned short*)(w + 75497472);    // 33.5 MB: r = sigmoid(xr@Wr^T)
  float*          CARR = (float*)(w + 109051904);            // 2 MB carries (in-place -> carry-in)

  prep_kernel<<<M_TOTAL/8 + 4096, 256, 0, stream>>>(x, lnw, lnb, tmk, tmv, tmr, XK, XV, XR,
                                                    Wk, Wv, Wr, Wo, WC);

  gemm_kr_kernel<<<dim3(512,1,2), 256, 0, stream>>>(XK, XR, WC, WC + (size_t)2*1048576, KB, RB);
  gemm_v_kernel<<<512, 256, 0, stream>>>(XV, WC + (size_t)1048576, KB);

  scan_p1_kernel<<<BATCH*NC, 256, 0, stream>>>(KB, dw, CARR);
  scan_p2_kernel<<<32, 256, 0, stream>>>(dw, CARR);
  scan_p3_kernel<<<BATCH*NC, 256, 0, stream>>>(KB, dw, CARR, sseq, finalS, SB16);

  gemm_out_kernel<<<512, 256, 0, stream>>>(SB16, WC + (size_t)3*1048576, x, RB, out);
}

// Round 13
// 243.714 us; speedup vs baseline: 1.0424x; 1.0424x over previous
//
#include <hip/hip_runtime.h>
#include <cstdint>

#define D_MODEL 1024
#define SEQ 2048
#define BATCH 8
#define M_TOTAL (BATCH*SEQ)   // 16384
#define NC 64                 // scan chunks per sequence
#define CL (SEQ/NC)           // 32 steps per chunk

typedef float f32x4 __attribute__((ext_vector_type(4)));
typedef short bf16x8 __attribute__((ext_vector_type(8)));
typedef unsigned short u16x4 __attribute__((ext_vector_type(4)));

__device__ __forceinline__ float b2f(unsigned short s){
  union { float f; unsigned u; } z; z.u = ((unsigned)s) << 16; return z.f;
}
__device__ __forceinline__ unsigned short f2b(float f){
  union { float f; unsigned u; } z; z.f = f;
  unsigned u = z.u;
  u += 0x7fffu + ((u >> 16) & 1u);   // round-to-nearest-even
  return (unsigned short)(u >> 16);
}
__device__ __forceinline__ float sigmoidf_(float v){
  return 1.0f / (1.0f + __expf(-v));
}
__device__ __forceinline__ void gld_lds16(const void* g, void* l){
  __builtin_amdgcn_global_load_lds((const __attribute__((address_space(1))) unsigned int*)g,
                                   (__attribute__((address_space(3))) unsigned int*)l,
                                   16, 0, 0);
}

// XCD-chunked swizzle for 512-block GEMM grid (64 m-panels x 8 n-panels). [T1]
__device__ __forceinline__ void swz_mn(int bid, int& m0, int& n0){
  int xcd = bid & 7;
  int loc = bid >> 3;              // 0..63
  int wg  = xcd*64 + loc;
  m0 = (wg >> 3) * 256;
  n0 = (wg & 7) * 128;
}

// ---------------- fused prep: lnmix (blocks 0..2047) + weight convert (2048..6143) ----------------
__global__ __launch_bounds__(256) void prep_kernel(const float* __restrict__ x,
                                                   const float* __restrict__ lnw, const float* __restrict__ lnb,
                                                   const float* __restrict__ tmk, const float* __restrict__ tmv,
                                                   const float* __restrict__ tmr,
                                                   unsigned short* __restrict__ XK, unsigned short* __restrict__ XV,
                                                   unsigned short* __restrict__ XR,
                                                   const float* __restrict__ W0, const float* __restrict__ W1,
                                                   const float* __restrict__ W2, const float* __restrict__ W3,
                                                   unsigned short* __restrict__ WC){
  int tid = threadIdx.x;
  if (blockIdx.x >= M_TOTAL/8){
    // ---- weight convert fp32 -> bf16 ----
    int t = blockIdx.x - M_TOTAL/8;      // 0..4095
    int mat = t >> 10;
    const float* src = (mat==0) ? W0 : (mat==1) ? W1 : (mat==2) ? W2 : W3;
    size_t i = ((size_t)(t & 1023)*256 + tid)*4;
    f32x4 v = *(const f32x4*)(src + i);
    u16x4 o; o[0]=f2b(v[0]); o[1]=f2b(v[1]); o[2]=f2b(v[2]); o[3]=f2b(v[3]);
    *(u16x4*)(WC + (size_t)mat*1048576 + i) = o;
    return;
  }
  // ---- LayerNorm + time-mix, row-blocked (8 rows + halo) ----
  int r0 = blockIdx.x * 8;
  bool seqfirst = (r0 & (SEQ-1)) == 0;
  size_t col = (size_t)tid*4;

  f32x4 xr[9];
  float s1[9], s2[9];
  #pragma unroll
  for (int i=0;i<9;i++){
    if (i==0 && seqfirst){
      xr[0][0]=0.f; xr[0][1]=0.f; xr[0][2]=0.f; xr[0][3]=0.f;
    } else {
      xr[i] = *(const f32x4*)(x + (size_t)(r0-1+i)*D_MODEL + col);
    }
    s1[i] = xr[i][0]+xr[i][1]+xr[i][2]+xr[i][3];
    s2[i] = xr[i][0]*xr[i][0]+xr[i][1]*xr[i][1]+xr[i][2]*xr[i][2]+xr[i][3]*xr[i][3];
  }
  #pragma unroll
  for (int off = 32; off > 0; off >>= 1){
    #pragma unroll
    for (int i=0;i<9;i++){
      s1[i] += __shfl_xor(s1[i], off);
      s2[i] += __shfl_xor(s2[i], off);
    }
  }
  __shared__ float red[4][18];
  int w = tid >> 6, lane = tid & 63;
  if (lane == 0){
    #pragma unroll
    for (int i=0;i<9;i++){ red[w][i]=s1[i]; red[w][9+i]=s2[i]; }
  }
  __syncthreads();
  float mean[9], rstd[9];
  #pragma unroll
  for (int i=0;i<9;i++){
    float a = red[0][i]+red[1][i]+red[2][i]+red[3][i];
    float b = red[0][9+i]+red[1][9+i]+red[2][9+i]+red[3][9+i];
    mean[i] = a*(1.0f/1024.0f);
    float var = b*(1.0f/1024.0f) - mean[i]*mean[i];
    rstd[i] = rsqrtf(var + 1e-5f);
  }

  f32x4 wv = *(const f32x4*)(lnw + col);
  f32x4 bv = *(const f32x4*)(lnb + col);
  f32x4 k4 = *(const f32x4*)(tmk + col);
  f32x4 v4 = *(const f32x4*)(tmv + col);
  f32x4 r4 = *(const f32x4*)(tmr + col);

  f32x4 np;
  if (seqfirst){ np[0]=0.f; np[1]=0.f; np[2]=0.f; np[3]=0.f; }
  else {
    #pragma unroll
    for (int j=0;j<4;j++) np[j] = (xr[0][j]-mean[0])*rstd[0]*wv[j] + bv[j];
  }
  #pragma unroll
  for (int i=0;i<8;i++){
    f32x4 nc;
    #pragma unroll
    for (int j=0;j<4;j++) nc[j] = (xr[i+1][j]-mean[i+1])*rstd[i+1]*wv[j] + bv[j];
    u16x4 ok, ov, orr;
    #pragma unroll
    for (int j=0;j<4;j++){
      ok[j]  = f2b(np[j] + k4[j]*(nc[j]-np[j]));
      ov[j]  = f2b(np[j] + v4[j]*(nc[j]-np[j]));
      orr[j] = f2b(np[j] + r4[j]*(nc[j]-np[j]));
    }
    size_t base = (size_t)(r0+i)*D_MODEL + col;
    *(u16x4*)(XK + base) = ok;
    *(u16x4*)(XV + base) = ov;
    *(u16x4*)(XR + base) = orr;
    np = nc;
  }
}

// ---------------- 256x128 GEMM core: BK=64, 4 waves (2m x 2n, wave tile 128x64),
// SINGLE 48KB LDS buffer -> 2 blocks/CU for inter-block overlap (m114/m97).
// Per K-tile: 4-phase read/MFMA schedule; STAGE(kt+1) issued after ph3's
// reads-complete barrier (lgkm0 before bar -> overwrite race-free); 32
// register-only MFMAs of cover; vmcnt(0)+bar at tile top (drain overlapped by
// the co-resident block). 2-way-free XOR swizzle. [r8 core, best measured;
// r12 showed the 4-phase pacing barriers are load-bearing -- do not remove]
__device__ __forceinline__ void gemm256_core(const unsigned short* __restrict__ A,
                                             const unsigned short* __restrict__ W,
                                             int m0, int n0, int tid,
                                             unsigned short* As, unsigned short* Bs,
                                             f32x4 (&acc)[8][4]){
  int wid = tid >> 6, lane = tid & 63;
  int wm = wid >> 1, wn = wid & 1;        // 2 x 2 waves
  int fr = lane & 15, fg = lane >> 4;

  // staging offsets: A 8 chunks/thread, B 4 chunks/thread per K-tile.
  // source pre-swizzled; LDS linear (gld_lds constraint, both-sides rule).
  int offAg[8], offBg[4];
  #pragma unroll
  for (int it = 0; it < 8; ++it){
    int chunk = it*256 + tid;          // 0..2047
    int row = chunk >> 3;              // 0..255
    int cg = (chunk & 7) ^ (row & 7);
    offAg[it] = (m0+row)*D_MODEL + cg*8;
  }
  #pragma unroll
  for (int it = 0; it < 4; ++it){
    int chunk = it*256 + tid;          // 0..1023
    int row = chunk >> 3;              // 0..127
    int cg = (chunk & 7) ^ (row & 7);
    offBg[it] = (n0+row)*D_MODEL + cg*8;
  }

  #define STAGE(kt_) { \
    _Pragma("unroll") \
    for (int it = 0; it < 8; ++it) \
      gld_lds16(A + offAg[it] + (kt_)*64, &As[(it*256+tid)*8]); \
    _Pragma("unroll") \
    for (int it = 0; it < 4; ++it) \
      gld_lds16(W + offBg[it] + (kt_)*64, &Bs[(it*256+tid)*8]); \
  }

  STAGE(0);

  bf16x8 aL[4][2], aH[4][2], bL[2][2], bH[2][2];

  #pragma unroll 1
  for (int kt = 0; kt < 16; ++kt){
    // all 12 staging loads for tile kt retired (own) + all waves' (barrier)
    asm volatile("s_waitcnt vmcnt(0)" ::: "memory");
    __builtin_amdgcn_s_barrier();
    asm volatile("" ::: "memory");

    // ---- phase 1: read aL(8) + bL(4); MFMA q0 ----
    #pragma unroll
    for (int mi=0; mi<4; ++mi)
      #pragma unroll
      for (int ks=0; ks<2; ++ks){
        int r = wm*128 + mi*16 + fr;
        aL[mi][ks] = *(const bf16x8*)(&As[r*64 + (((ks*4+fg)^(r&7))<<3)]);
      }
    #pragma unroll
    for (int ni=0; ni<2; ++ni)
      #pragma unroll
      for (int ks=0; ks<2; ++ks){
        int r = wn*64 + ni*16 + fr;
        bL[ni][ks] = *(const bf16x8*)(&Bs[r*64 + (((ks*4+fg)^(r&7))<<3)]);
      }
    __builtin_amdgcn_s_barrier();
    asm volatile("s_waitcnt lgkmcnt(0)" ::: "memory");
    __builtin_amdgcn_s_setprio(1);
    #pragma unroll
    for (int mi=0; mi<4; ++mi)
      #pragma unroll
      for (int ni=0; ni<2; ++ni)
        #pragma unroll
        for (int ks=0; ks<2; ++ks)
          acc[mi][ni] = __builtin_amdgcn_mfma_f32_16x16x32_bf16(aL[mi][ks], bL[ni][ks], acc[mi][ni], 0, 0, 0);
    __builtin_amdgcn_s_setprio(0);
    __builtin_amdgcn_s_barrier();

    // ---- phase 2: read bH(4); MFMA q1 ----
    #pragma unroll
    for (int ni=0; ni<2; ++ni)
      #pragma unroll
      for (int ks=0; ks<2; ++ks){
        int r = wn*64 + (ni+2)*16 + fr;
        bH[ni][ks] = *(const bf16x8*)(&Bs[r*64 + (((ks*4+fg)^(r&7))<<3)]);
      }
    __builtin_amdgcn_s_barrier();
    asm volatile("s_waitcnt lgkmcnt(0)" ::: "memory");
    __builtin_amdgcn_s_setprio(1);
    #pragma unroll
    for (int mi=0; mi<4; ++mi)
      #pragma unroll
      for (int ni=0; ni<2; ++ni)
        #pragma unroll
        for (int ks=0; ks<2; ++ks)
          acc[mi][ni+2] = __builtin_amdgcn_mfma_f32_16x16x32_bf16(aL[mi][ks], bH[ni][ks], acc[mi][ni+2], 0, 0, 0);
    __builtin_amdgcn_s_setprio(0);
    __builtin_amdgcn_s_barrier();

    // ---- phase 3: read aH(8); lgkm(0) BEFORE barrier -> after this barrier
    // every wave's reads of the buffer are complete -> STAGE overwrite safe ----
    #pragma unroll
    for (int mi=0; mi<4; ++mi)
      #pragma unroll
      for (int ks=0; ks<2; ++ks){
        int r = wm*128 + (mi+4)*16 + fr;
        aH[mi][ks] = *(const bf16x8*)(&As[r*64 + (((ks*4+fg)^(r&7))<<3)]);
      }
    asm volatile("s_waitcnt lgkmcnt(0)" ::: "memory");
    __builtin_amdgcn_s_barrier();
    asm volatile("" ::: "memory");

    if (kt < 15) STAGE(kt+1);   // 12 loads in flight under 32 reg-only MFMAs + other block

    __builtin_amdgcn_s_setprio(1);
    #pragma unroll
    for (int mi=0; mi<4; ++mi)
      #pragma unroll
      for (int ni=0; ni<2; ++ni)
        #pragma unroll
        for (int ks=0; ks<2; ++ks)
          acc[mi+4][ni+2] = __builtin_amdgcn_mfma_f32_16x16x32_bf16(aH[mi][ks], bH[ni][ks], acc[mi+4][ni+2], 0, 0, 0);
    #pragma unroll
    for (int mi=0; mi<4; ++mi)
      #pragma unroll
      for (int ni=0; ni<2; ++ni)
        #pragma unroll
        for (int ks=0; ks<2; ++ks)
          acc[mi+4][ni] = __builtin_amdgcn_mfma_f32_16x16x32_bf16(aH[mi][ks], bL[ni][ks], acc[mi+4][ni], 0, 0, 0);
    __builtin_amdgcn_s_setprio(0);
  }
  #undef STAGE
}

// ---------------- k and r GEMMs: z=0 k->KB, z=1 sigmoid r->RB ----------------
__global__ __launch_bounds__(256, 2) void gemm_kr_kernel(const unsigned short* __restrict__ XK,
                                                         const unsigned short* __restrict__ XR,
                                                         const unsigned short* __restrict__ Wk,
                                                         const unsigned short* __restrict__ Wr,
                                                         unsigned short* __restrict__ KB,
                                                         unsigned short* __restrict__ RB){
  __shared__ alignas(16) unsigned short As[16384];  // 32 KiB
  __shared__ alignas(16) unsigned short Bs[8192];   // 16 KiB
  int m0, n0; swz_mn(blockIdx.x, m0, n0);
  int z = blockIdx.z;
  int tid = threadIdx.x;
  const unsigned short* A = z ? XR : XK;
  const unsigned short* W = z ? Wr : Wk;
  unsigned short* O       = z ? RB : KB;

  f32x4 acc[8][4];
  #pragma unroll
  for (int i=0;i<8;i++)
    #pragma unroll
    for (int j=0;j<4;j++){ acc[i][j][0]=0.f; acc[i][j][1]=0.f; acc[i][j][2]=0.f; acc[i][j][3]=0.f; }

  gemm256_core(A, W, m0, n0, tid, As, Bs, acc);

  int wid = tid >> 6, lane = tid & 63;
  int wm = wid >> 1, wn = wid & 1;
  int fr = lane & 15, fg = lane >> 4;
  #pragma unroll
  for (int mi=0; mi<8; ++mi){
    #pragma unroll
    for (int ni=0; ni<4; ++ni){
      int c = n0 + wn*64 + ni*16 + fr;
      #pragma unroll
      for (int j=0; j<4; ++j){
        int r = m0 + wm*128 + mi*16 + fg*4 + j;
        size_t idx = (size_t)r*D_MODEL + c;
        float val = acc[mi][ni][j];
        if (z) val = sigmoidf_(val);
        O[idx] = f2b(val);
      }
    }
  }
}

// ---------------- v GEMM: kv = v*k RMW into KB (k from prior dispatch) ----------------
__global__ __launch_bounds__(256, 2) void gemm_v_kernel(const unsigned short* __restrict__ XV,
                                                        const unsigned short* __restrict__ Wv,
                                                        unsigned short* __restrict__ KB){
  __shared__ alignas(16) unsigned short As[16384];
  __shared__ alignas(16) unsigned short Bs[8192];
  int m0, n0; swz_mn(blockIdx.x, m0, n0);
  int tid = threadIdx.x;

  f32x4 acc[8][4];
  #pragma unroll
  for (int i=0;i<8;i++)
    #pragma unroll
    for (int j=0;j<4;j++){ acc[i][j][0]=0.f; acc[i][j][1]=0.f; acc[i][j][2]=0.f; acc[i][j][3]=0.f; }

  gemm256_core(XV, Wv, m0, n0, tid, As, Bs, acc);

  int wid = tid >> 6, lane = tid & 63;
  int wm = wid >> 1, wn = wid & 1;
  int fr = lane & 15, fg = lane >> 4;
  #pragma unroll
  for (int mi=0; mi<8; ++mi){
    #pragma unroll
    for (int ni=0; ni<4; ++ni){
      int c = n0 + wn*64 + ni*16 + fr;
      #pragma unroll
      for (int j=0; j<4; ++j){
        int r = m0 + wm*128 + mi*16 + fg*4 + j;
        size_t idx = (size_t)r*D_MODEL + c;
        KB[idx] = f2b(acc[mi][ni][j] * b2f(KB[idx]));   // kv = v*k
      }
    }
  }
}

// ---------------- out GEMM: o = S_seq @ Wo^T ; out = x + r*o ----------------
__global__ __launch_bounds__(256, 2) void gemm_out_kernel(const unsigned short* __restrict__ Sb,
                                                          const unsigned short* __restrict__ Wo,
                                                          const float* __restrict__ x,
                                                          const unsigned short* __restrict__ RB,
                                                          float* __restrict__ out){
  __shared__ alignas(16) unsigned short As[16384];
  __shared__ alignas(16) unsigned short Bs[8192];
  int m0, n0; swz_mn(blockIdx.x, m0, n0);
  int tid = threadIdx.x;

  f32x4 acc[8][4];
  #pragma unroll
  for (int i=0;i<8;i++)
    #pragma unroll
    for (int j=0;j<4;j++){ acc[i][j][0]=0.f; acc[i][j][1]=0.f; acc[i][j][2]=0.f; acc[i][j][3]=0.f; }

  gemm256_core(Sb, Wo, m0, n0, tid, As, Bs, acc);

  int wid = tid >> 6, lane = tid & 63;
  int wm = wid >> 1, wn = wid & 1;
  int fr = lane & 15, fg = lane >> 4;
  #pragma unroll
  for (int mi=0; mi<8; ++mi){
    #pragma unroll
    for (int ni=0; ni<4; ++ni){
      int c = n0 + wn*64 + ni*16 + fr;
      #pragma unroll
      for (int j=0; j<4; ++j){
        int r = m0 + wm*128 + mi*16 + fg*4 + j;
        size_t idx = (size_t)r*D_MODEL + c;
        float rr = b2f(RB[idx]);
        out[idx] = x[idx] + rr * acc[mi][ni][j];
      }
    }
  }
}

// ---------------- scan phase 1: per-chunk carries (reads kv) ----------------
__global__ __launch_bounds__(256) void scan_p1_kernel(const unsigned short* __restrict__ kv,
                                                      const float* __restrict__ dw,
                                                      float* __restrict__ carr){
  int bc = blockIdx.x;            // b*NC + c
  int b = bc >> 6, c = bc & (NC-1);
  int d0 = threadIdx.x * 4;
  float dx = sigmoidf_(dw[d0+0]);
  float dy = sigmoidf_(dw[d0+1]);
  float dz = sigmoidf_(dw[d0+2]);
  float dwv = sigmoidf_(dw[d0+3]);
  float Sx=0.f, Sy=0.f, Sz=0.f, Sw=0.f;
  size_t base = ((size_t)(b*SEQ + c*CL))*D_MODEL + d0;
  for (int i=0;i<CL;i++){
    u16x4 k4 = *(const u16x4*)(kv + base);
    Sx = dx*Sx + b2f(k4[0]);
    Sy = dy*Sy + b2f(k4[1]);
    Sz = dz*Sz + b2f(k4[2]);
    Sw = dwv*Sw + b2f(k4[3]);
    base += D_MODEL;
  }
  f32x4 o; o[0]=Sx; o[1]=Sy; o[2]=Sz; o[3]=Sw;
  *(f32x4*)(carr + (size_t)bc*D_MODEL + d0) = o;
}

// ---------------- scan phase 2: cross-chunk exclusive scan (in-place) ----------------
__global__ __launch_bounds__(256) void scan_p2_kernel(const float* __restrict__ dw, float* __restrict__ carr){
  int gid = blockIdx.x*256 + threadIdx.x;   // 0..8191
  int b = gid >> 10, d = gid & (D_MODEL-1);
  float dec = sigmoidf_(dw[d]);
  float dL = dec;
  #pragma unroll
  for (int i=0;i<5;i++) dL *= dL;           // dec^32
  float S = 0.f;
  for (int c=0;c<NC;c++){
    size_t idx = ((size_t)(b*NC + c))*D_MODEL + d;
    float cr = carr[idx];
    carr[idx] = S;                          // becomes carry-in
    S = dL*S + cr;
  }
}

// ---------------- scan phase 3: prefix with carry-in; write S_seq fp32 + bf16 ----------------
__global__ __launch_bounds__(256) void scan_p3_kernel(const unsigned short* __restrict__ kv,
                                                      const float* __restrict__ dw,
                                                      const float* __restrict__ cin,
                                                      float* __restrict__ sseq,
                                                      float* __restrict__ finalS,
                                                      unsigned short* __restrict__ sb16){
  int bc = blockIdx.x;
  int b = bc >> 6, c = bc & (NC-1);
  int d0 = threadIdx.x * 4;
  float dx = sigmoidf_(dw[d0+0]);
  float dy = sigmoidf_(dw[d0+1]);
  float dz = sigmoidf_(dw[d0+2]);
  float dwv = sigmoidf_(dw[d0+3]);
  f32x4 S = *(const f32x4*)(cin + (size_t)bc*D_MODEL + d0);
  size_t base = ((size_t)(b*SEQ + c*CL))*D_MODEL + d0;
  for (int i=0;i<CL;i++){
    u16x4 k4 = *(const u16x4*)(kv + base);
    S[0] = dx*S[0] + b2f(k4[0]);
    S[1] = dy*S[1] + b2f(k4[1]);
    S[2] = dz*S[2] + b2f(k4[2]);
    S[3] = dwv*S[3] + b2f(k4[3]);
    *(f32x4*)(sseq + base) = S;
    u16x4 s4; s4[0]=f2b(S[0]); s4[1]=f2b(S[1]); s4[2]=f2b(S[2]); s4[3]=f2b(S[3]);
    *(u16x4*)(sb16 + base) = s4;
    base += D_MODEL;
  }
  if (c == NC-1)
    *(f32x4*)(finalS + (size_t)b*D_MODEL + d0) = S;
}

extern "C" void kernel_launch(void* const* d_in, const int* in_sizes, int n_in,
                              void* d_out, int out_size, void* d_ws, size_t ws_size,
                              hipStream_t stream){
  const float* x   = (const float*)d_in[0];
  const float* lnw = (const float*)d_in[1];
  const float* lnb = (const float*)d_in[2];
  const float* tmk = (const float*)d_in[3];
  const float* tmv = (const float*)d_in[4];
  const float* tmr = (const float*)d_in[5];
  const float* dw  = (const float*)d_in[6];
  const float* Wk  = (const float*)d_in[7];
  const float* Wv  = (const float*)d_in[8];
  const float* Wr  = (const float*)d_in[9];
  const float* Wo  = (const float*)d_in[10];

  float* out    = (float*)d_out;
  float* finalS = out + (size_t)M_TOTAL*D_MODEL;
  float* sseq   = finalS + (size_t)BATCH*D_MODEL;

  // d_out doubles as GEMM-phase scratch:
  //   XK = out[0 .. 33.5MB)           dead before gemm_out writes out
  //   XV = out[33.5MB .. 67.1MB)      dead before gemm_out writes out
  //   XR = sseq region (first 33.5MB) dead before scan_p3 writes sseq
  unsigned short* XK = (unsigned short*)d_out;
  unsigned short* XV = (unsigned short*)((char*)d_out + 33554432);
  unsigned short* XR = (unsigned short*)sseq;

  char* w = (char*)d_ws;
  unsigned short* WC   = (unsigned short*)(w + 0);           // 8.4 MB (Wk,Wv,Wr,Wo bf16)
  unsigned short* SB16 = (unsigned short*)(w + 8388608);     // 33.5 MB: S bf16 for out-GEMM
  unsigned short* KB   = (unsigned short*)(w + 41943040);    // 33.5 MB: k, then kv (RMW)
  unsigned short* RB   = (unsigned short*)(w + 75497472);    // 33.5 MB: r = sigmoid(xr@Wr^T)
  float*          CARR = (float*)(w + 109051904);            // 2 MB carries (in-place -> carry-in)

  prep_kernel<<<M_TOTAL/8 + 4096, 256, 0, stream>>>(x, lnw, lnb, tmk, tmv, tmr, XK, XV, XR,
                                                    Wk, Wv, Wr, Wo, WC);

  gemm_kr_kernel<<<dim3(512,1,2), 256, 0, stream>>>(XK, XR, WC, WC + (size_t)2*1048576, KB, RB);
  gemm_v_kernel<<<512, 256, 0, stream>>>(XV, WC + (size_t)1048576, KB);

  scan_p1_kernel<<<BATCH*NC, 256, 0, stream>>>(KB, dw, CARR);
  scan_p2_kernel<<<32, 256, 0, stream>>>(dw, CARR);
  scan_p3_kernel<<<BATCH*NC, 256, 0, stream>>>(KB, dw, CARR, sseq, finalS, SB16);

  gemm_out_kernel<<<512, 256, 0, stream>>>(SB16, WC + (size_t)3*1048576, x, RB, out);
}